// Round 8
// baseline (438.251 us; speedup 1.0000x reference)
//
#include <hip/hip_runtime.h>
#include <hip/hip_cooperative_groups.h>
#include <cstddef>

namespace cg = cooperative_groups;

#define EPS1f 1e-6f
#define WDf   1e-5f

constexpr int Bsz = 512, Csz = 500, Zsz = 64, Ssz = 100;

typedef short bf16x8 __attribute__((ext_vector_type(8)));
typedef float f32x4 __attribute__((ext_vector_type(4)));

struct MegaArgs {
  const float *X, *Y, *noise, *W1, *b1, *W2, *b2, *W3, *b3, *Wmu, *bmu, *rss;
  float *h1, *h2, *feat, *sqrtcov, *rmuB, *yB, *ce_part, *nll_b, *l2_part, *lp_part;
  short *Rb, *nfB;
  float *out_prob, *out4;
};

__device__ inline short f2bf(float f) {
  union { float f; unsigned u; } v; v.f = f;
  unsigned r = (v.u + 0x7fffu + ((v.u >> 16) & 1u)) >> 16;   // RNE
  return (short)r;
}

// log( Phi(t)*(1-eps) + eps/2 )  via A&S 7.1.26 erfc approx (|err|<=1.5e-7)
__device__ inline float log_probit(float t) {
  const float u = t * -0.70710678118654752f;
  const float au = fabsf(u);
  const float s = 1.f / fmaf(0.3275911f, au, 1.f);
  float p = fmaf(1.061405429f, s, -1.453152027f);
  p = fmaf(p, s, 1.421413741f);
  p = fmaf(p, s, -0.284496736f);
  p = fmaf(p, s, 0.254829592f);
  p = p * s;
  const float e = __expf(-au * au);
  const float f = p * e;
  const float erfc_u = (u < 0.f) ? (2.f - f) : f;
  const float E = fmaf(0.5f * erfc_u, 1.f - EPS1f, 0.5f * EPS1f);
  return __logf(E);
}

__device__ inline float block_reduce_sum(float v, float* red) {
  #pragma unroll
  for (int off = 32; off > 0; off >>= 1) v += __shfl_down(v, off, 64);
  const int lane = threadIdx.x & 63, wid = threadIdx.x >> 6;
  __syncthreads();
  if (lane == 0) red[wid] = v;
  __syncthreads();
  float r = 0.f;
  if (threadIdx.x == 0) {
    for (int i = 0; i < 4; ++i) r += red[i];
  }
  __syncthreads();
  return r;   // valid in thread 0 only
}

// ---------------- 32x32 double-buffered GEMM body ----------------
__device__ __forceinline__ void dev_gemm32(
    const float* __restrict__ A, const float* __restrict__ W,
    const float* __restrict__ bias, float* __restrict__ out,
    int M, int N, int K, int bn0, int bm0, float* smem, bool relu) {
  float* As_ = smem;            // 2*1152
  float* Ws_ = smem + 2304;     // 2*1152
  const int tid = threadIdx.x;
  const int bn = bn0 * 32, bm = bm0 * 32;
  const int sm = tid >> 3, sk4 = (tid & 7) * 4;
  const int sk = tid >> 3, sn4 = (tid & 7) * 4;
  const int tn = tid & 15, tm = tid >> 4;
  #define AS_(b, k, m) As_[(b) * 1152 + (k) * 36 + (m)]
  #define WS_(b, k, n) Ws_[(b) * 1152 + (k) * 36 + (n)]
  auto loadW = [&](int kt, float4& wv) {
    const float* wrow = W + (size_t)(kt + sk) * N;
    const int nn = bn + sn4;
    if (nn + 3 < N) wv = *reinterpret_cast<const float4*>(wrow + nn);
    else {
      wv.x = (nn + 0 < N) ? wrow[nn + 0] : 0.f;
      wv.y = (nn + 1 < N) ? wrow[nn + 1] : 0.f;
      wv.z = (nn + 2 < N) ? wrow[nn + 2] : 0.f;
      wv.w = (nn + 3 < N) ? wrow[nn + 3] : 0.f;
    }
  };
  __syncthreads();   // smem reuse guard
  {
    float4 av = *reinterpret_cast<const float4*>(A + (size_t)(bm + sm) * K + sk4);
    float4 wv; loadW(0, wv);
    AS_(0, sk4 + 0, sm) = av.x; AS_(0, sk4 + 1, sm) = av.y;
    AS_(0, sk4 + 2, sm) = av.z; AS_(0, sk4 + 3, sm) = av.w;
    *reinterpret_cast<float4*>(&WS_(0, sk, sn4)) = wv;
  }
  __syncthreads();
  float acc[2][2] = {};
  int pb = 0;
  for (int kt = 0; kt < K; kt += 32) {
    const bool more = (kt + 32) < K;
    float4 av2, wv2;
    if (more) {
      av2 = *reinterpret_cast<const float4*>(A + (size_t)(bm + sm) * K + kt + 32 + sk4);
      loadW(kt + 32, wv2);
    }
    #pragma unroll
    for (int k = 0; k < 32; ++k) {
      const float2 a = *reinterpret_cast<const float2*>(&AS_(pb, k, tm * 2));
      const float2 w = *reinterpret_cast<const float2*>(&WS_(pb, k, tn * 2));
      acc[0][0] = fmaf(a.x, w.x, acc[0][0]);
      acc[0][1] = fmaf(a.x, w.y, acc[0][1]);
      acc[1][0] = fmaf(a.y, w.x, acc[1][0]);
      acc[1][1] = fmaf(a.y, w.y, acc[1][1]);
    }
    if (more) {
      const int nb2 = pb ^ 1;
      AS_(nb2, sk4 + 0, sm) = av2.x; AS_(nb2, sk4 + 1, sm) = av2.y;
      AS_(nb2, sk4 + 2, sm) = av2.z; AS_(nb2, sk4 + 3, sm) = av2.w;
      *reinterpret_cast<float4*>(&WS_(nb2, sk, sn4)) = wv2;
      __syncthreads();
      pb = nb2;
    }
  }
  #pragma unroll
  for (int j = 0; j < 2; ++j) {
    const int n = bn + tn * 2 + j;
    if (n >= N) continue;
    const float bv = bias[n];
    #pragma unroll
    for (int i = 0; i < 2; ++i) {
      const int m = bm + tm * 2 + i;
      float v = acc[i][j] + bv;
      if (relu) v = fmaxf(v, 0.f);
      out[(size_t)m * N + n] = v;
    }
  }
  #undef AS_
  #undef WS_
}

// ---------------- MU GEMM body: -> indiv_prob, CE partials, rmuB/yB ----------------
__device__ __forceinline__ void dev_gemm32_mu(const MegaArgs& a, int bn0, int bm0, float* smem) {
  const float* A = a.feat; const float* W = a.Wmu; const float* bias = a.bmu;
  const int N = Csz, K = 256;
  float* As_ = smem;
  float* Ws_ = smem + 2304;
  const int tid = threadIdx.x;
  const int bn = bn0 * 32, bm = bm0 * 32;
  const int sm = tid >> 3, sk4 = (tid & 7) * 4;
  const int sk = tid >> 3, sn4 = (tid & 7) * 4;
  const int tn = tid & 15, tm = tid >> 4;
  #define AS_(b, k, m) As_[(b) * 1152 + (k) * 36 + (m)]
  #define WS_(b, k, n) Ws_[(b) * 1152 + (k) * 36 + (n)]
  auto loadW = [&](int kt, float4& wv) {
    const float* wrow = W + (size_t)(kt + sk) * N;
    const int nn = bn + sn4;
    if (nn + 3 < N) wv = *reinterpret_cast<const float4*>(wrow + nn);
    else {
      wv.x = (nn + 0 < N) ? wrow[nn + 0] : 0.f;
      wv.y = (nn + 1 < N) ? wrow[nn + 1] : 0.f;
      wv.z = (nn + 2 < N) ? wrow[nn + 2] : 0.f;
      wv.w = (nn + 3 < N) ? wrow[nn + 3] : 0.f;
    }
  };
  __syncthreads();
  {
    float4 av = *reinterpret_cast<const float4*>(A + (size_t)(bm + sm) * K + sk4);
    float4 wv; loadW(0, wv);
    AS_(0, sk4 + 0, sm) = av.x; AS_(0, sk4 + 1, sm) = av.y;
    AS_(0, sk4 + 2, sm) = av.z; AS_(0, sk4 + 3, sm) = av.w;
    *reinterpret_cast<float4*>(&WS_(0, sk, sn4)) = wv;
  }
  __syncthreads();
  float acc[2][2] = {};
  int pb = 0;
  for (int kt = 0; kt < K; kt += 32) {
    const bool more = (kt + 32) < K;
    float4 av2, wv2;
    if (more) {
      av2 = *reinterpret_cast<const float4*>(A + (size_t)(bm + sm) * K + kt + 32 + sk4);
      loadW(kt + 32, wv2);
    }
    #pragma unroll
    for (int k = 0; k < 32; ++k) {
      const float2 aa = *reinterpret_cast<const float2*>(&AS_(pb, k, tm * 2));
      const float2 ww = *reinterpret_cast<const float2*>(&WS_(pb, k, tn * 2));
      acc[0][0] = fmaf(aa.x, ww.x, acc[0][0]);
      acc[0][1] = fmaf(aa.x, ww.y, acc[0][1]);
      acc[1][0] = fmaf(aa.y, ww.x, acc[1][0]);
      acc[1][1] = fmaf(aa.y, ww.y, acc[1][1]);
    }
    if (more) {
      const int nb2 = pb ^ 1;
      AS_(nb2, sk4 + 0, sm) = av2.x; AS_(nb2, sk4 + 1, sm) = av2.y;
      AS_(nb2, sk4 + 2, sm) = av2.z; AS_(nb2, sk4 + 3, sm) = av2.w;
      *reinterpret_cast<float4*>(&WS_(nb2, sk, sn4)) = wv2;
      __syncthreads();
      pb = nb2;
    }
  }
  float ce2[2] = {0.f, 0.f};
  #pragma unroll
  for (int i = 0; i < 2; ++i) {
    const int m = bm + tm * 2 + i;
    #pragma unroll
    for (int j = 0; j < 2; ++j) {
      const int n = bn + tn * 2 + j;
      if (n < N) {
        const float v = acc[i][j] + bias[n];
        const float sp = 1.f / (1.f + __expf(-1.70169f * v));
        const float p = fmaf(sp, 1.f - EPS1f, 0.5f * EPS1f);
        const float q = fmaf(1.f - sp, 1.f - EPS1f, 0.5f * EPS1f);
        const float y = a.Y[(size_t)m * N + n];
        a.out_prob[(size_t)m * N + n] = p;
        ce2[i] += __logf((y > 0.5f) ? p : q);
        a.rmuB[(size_t)m * 512 + n] = v * a.sqrtcov[n];
        a.yB[(size_t)m * 512 + n] = y;
      }
    }
  }
  #pragma unroll
  for (int off = 1; off < 16; off <<= 1) {
    ce2[0] += __shfl_xor(ce2[0], off, 64);
    ce2[1] += __shfl_xor(ce2[1], off, 64);
  }
  if (tn == 0) {
    const int m0 = bm + tm * 2;
    a.ce_part[(size_t)bn0 * Bsz + m0] = ce2[0];
    a.ce_part[(size_t)bn0 * Bsz + m0 + 1] = ce2[1];
  }
  #undef AS_
  #undef WS_
}

// ---------------- noise -> bf16 MFMA-fragment layout (unit u in [0,800)) ----------------
__device__ __forceinline__ void dev_nprep(int u, int tid, const float* __restrict__ noise,
                                          short* __restrict__ nfB) {
  const int g = u * 256 + tid;
  const int s = g >> 11;
  const int r = g & 2047;
  const int bt = r >> 6;
  const int ln = r & 63;
  const int cl = ln & 15, grp = ln >> 4;
  const float* src = noise + ((size_t)(s * 512 + bt * 16 + cl) * 64 + grp * 8);
  const float4 a = *reinterpret_cast<const float4*>(src);
  const float4 b = *reinterpret_cast<const float4*>(src + 4);
  const float4 c = *reinterpret_cast<const float4*>(src + 32);
  const float4 d = *reinterpret_cast<const float4*>(src + 36);
  bf16x8* dst = reinterpret_cast<bf16x8*>(nfB);
  const int uo = (s * 32 + bt) * 128 + ln;
  dst[uo]      = bf16x8{ f2bf(a.x), f2bf(a.y), f2bf(a.z), f2bf(a.w),
                         f2bf(b.x), f2bf(b.y), f2bf(b.z), f2bf(b.w) };
  dst[uo + 64] = bf16x8{ f2bf(c.x), f2bf(c.y), f2bf(c.z), f2bf(c.w),
                         f2bf(d.x), f2bf(d.y), f2bf(d.z), f2bf(d.w) };
}

// ---------------- R -> bf16 + sqrt(cov_diag) (unit u in [0,8)) ----------------
__device__ __forceinline__ void dev_rprep(int u, int tid, const float* __restrict__ R,
                                          short* __restrict__ Rb, float* __restrict__ sqrtcov) {
  const int idx = u * 256 + tid;     // 0..2047
  const int c = idx >> 2;
  const int zq = (idx & 3) * 16;
  const bool cv = c < Csz;
  const float* src = R + (size_t)c * Zsz + zq;
  float4 r0, r1, r2, r3;
  if (cv) {
    r0 = *reinterpret_cast<const float4*>(src);
    r1 = *reinterpret_cast<const float4*>(src + 4);
    r2 = *reinterpret_cast<const float4*>(src + 8);
    r3 = *reinterpret_cast<const float4*>(src + 12);
  } else {
    r0 = r1 = r2 = r3 = make_float4(0.f, 0.f, 0.f, 0.f);
  }
  float ss = 0.f;
  ss = fmaf(r0.x, r0.x, ss); ss = fmaf(r0.y, r0.y, ss);
  ss = fmaf(r0.z, r0.z, ss); ss = fmaf(r0.w, r0.w, ss);
  ss = fmaf(r1.x, r1.x, ss); ss = fmaf(r1.y, r1.y, ss);
  ss = fmaf(r1.z, r1.z, ss); ss = fmaf(r1.w, r1.w, ss);
  ss = fmaf(r2.x, r2.x, ss); ss = fmaf(r2.y, r2.y, ss);
  ss = fmaf(r2.z, r2.z, ss); ss = fmaf(r2.w, r2.w, ss);
  ss = fmaf(r3.x, r3.x, ss); ss = fmaf(r3.y, r3.y, ss);
  ss = fmaf(r3.z, r3.z, ss); ss = fmaf(r3.w, r3.w, ss);
  short* dst = Rb + (size_t)c * Zsz + zq;
  *reinterpret_cast<bf16x8*>(dst) =
      bf16x8{ f2bf(r0.x), f2bf(r0.y), f2bf(r0.z), f2bf(r0.w),
              f2bf(r1.x), f2bf(r1.y), f2bf(r1.z), f2bf(r1.w) };
  *reinterpret_cast<bf16x8*>(dst + 8) =
      bf16x8{ f2bf(r2.x), f2bf(r2.y), f2bf(r2.z), f2bf(r2.w),
              f2bf(r3.x), f2bf(r3.y), f2bf(r3.z), f2bf(r3.w) };
  ss += __shfl_xor(ss, 1, 64);
  ss += __shfl_xor(ss, 2, 64);
  if ((idx & 3) == 0 && cv) sqrtcov[c] = sqrtf(1.f + ss);
}

// ---------------- L2 partials (unit u in [0,64)) ----------------
__device__ __forceinline__ void dev_l2(int u, int tid, const MegaArgs& a, float* smem) {
  const int gid = u * 256 + tid;
  const int stride = 64 * 256;
  float s = 0.f;
  for (int i = gid; i < 65536; i += stride) { float v = a.W1[i]; s = fmaf(v, v, s); }
  for (int i = gid; i < 32768; i += stride) { float v = a.W2[i]; s = fmaf(v, v, s); }
  for (int i = gid; i < 65536; i += stride) { float v = a.W3[i]; s = fmaf(v, v, s); }
  for (int i = gid; i < 128000; i += stride) { float v = a.Wmu[i]; s = fmaf(v, v, s); }
  const float tot = block_reduce_sum(s, smem);
  if (tid == 0) a.l2_part[u] = tot;
}

// ---------------- logprob unit: (bt, ctg) spatial tile, s in [lo,hi) ----------------
__device__ __forceinline__ void dev_logprob(int bt, int ctg, int lo, int hi, int tid,
                                            const short* __restrict__ nfB,
                                            const short* __restrict__ Rb,
                                            const float* __restrict__ rmuB,
                                            const float* __restrict__ yB,
                                            float* __restrict__ lp_part) {
  const int wid = tid >> 6;
  const int lane = tid & 63;
  const int cl = lane & 15, grp = lane >> 4;
  const int ct = ctg * 4 + wid;
  const int c0 = ct * 16, b0 = bt * 16;

  const bf16x8 Rf0 = *reinterpret_cast<const bf16x8*>(Rb + (size_t)(c0 + cl) * 64 + grp * 8);
  const bf16x8 Rf1 = *reinterpret_cast<const bf16x8*>(Rb + (size_t)(c0 + cl) * 64 + 32 + grp * 8);
  const int cb = c0 + grp * 4;
  const float4 rmu4 = *reinterpret_cast<const float4*>(rmuB + (size_t)(b0 + cl) * 512 + cb);
  const float4 y4   = *reinterpret_cast<const float4*>(yB + (size_t)(b0 + cl) * 512 + cb);
  const float sn0 = fmaf(2.f, y4.x, -1.f), sn1 = fmaf(2.f, y4.y, -1.f);
  const float sn2 = fmaf(2.f, y4.z, -1.f), sn3 = fmaf(2.f, y4.w, -1.f);
  const bool v0 = cb + 0 < Csz, v1 = cb + 1 < Csz, v2 = cb + 2 < Csz, v3 = cb + 3 < Csz;

  const bf16x8* nf = reinterpret_cast<const bf16x8*>(nfB);
  int base = (lo * 32 + bt) * 128 + lane;
  bf16x8 c0f = nf[base], c1f = nf[base + 64];

  for (int s = lo; s < hi; ++s) {
    const int nbase = base + 4096;
    bf16x8 p0, p1;
    if (s + 1 < hi) { p0 = nf[nbase]; p1 = nf[nbase + 64]; }
    f32x4 acc = {0.f, 0.f, 0.f, 0.f};
    acc = __builtin_amdgcn_mfma_f32_16x16x32_bf16(Rf0, c0f, acc, 0, 0, 0);
    acc = __builtin_amdgcn_mfma_f32_16x16x32_bf16(Rf1, c1f, acc, 0, 0, 0);
    float lpl = 0.f;
    lpl += v0 ? log_probit((acc[0] + rmu4.x) * sn0) : 0.f;
    lpl += v1 ? log_probit((acc[1] + rmu4.y) * sn1) : 0.f;
    lpl += v2 ? log_probit((acc[2] + rmu4.z) * sn2) : 0.f;
    lpl += v3 ? log_probit((acc[3] + rmu4.w) * sn3) : 0.f;
    lpl += __shfl_xor(lpl, 16, 64);
    lpl += __shfl_xor(lpl, 32, 64);
    if (lane < 16) lp_part[(size_t)(s * 32 + ct) * 512 + b0 + lane] = lpl;
    base = nbase; c0f = p0; c1f = p1;
  }
}

// ---------------- nll for one b: ct-sum + 256-wide LSE tree ----------------
__device__ __forceinline__ void dev_nll(int b, int tid, const float* __restrict__ lp_part,
                                        float* __restrict__ nll_b, float* smem) {
  __syncthreads();   // smem reuse guard
  float m = -3.0e38f, se = 0.f;
  if (tid < Ssz) {
    const float* p = lp_part + (size_t)tid * 16384 + b;
    float a0 = 0.f, a1 = 0.f, a2 = 0.f, a3 = 0.f;
    #pragma unroll
    for (int ct = 0; ct < 32; ct += 4) {
      a0 += p[(ct + 0) * 512];
      a1 += p[(ct + 1) * 512];
      a2 += p[(ct + 2) * 512];
      a3 += p[(ct + 3) * 512];
    }
    m = (a0 + a1) + (a2 + a3);
    se = 1.f;
  }
  float* sm = smem;
  float* ss = smem + 256;
  sm[tid] = m; ss[tid] = se;
  __syncthreads();
  #pragma unroll
  for (int off = 128; off > 0; off >>= 1) {
    if (tid < off) {
      const float m1 = sm[tid], m2 = sm[tid + off];
      const float M = fmaxf(m1, m2);
      ss[tid] = ss[tid] * __expf(m1 - M) + ss[tid + off] * __expf(m2 - M);
      sm[tid] = M;
    }
    __syncthreads();
  }
  if (tid == 0) nll_b[b] = -__logf(ss[0] * (1.f / (float)Ssz)) - sm[0];
}

// ---------------- final scalars (one block) ----------------
__device__ __forceinline__ void dev_finals(int tid, const MegaArgs& a, float* smem) {
  const float snll = block_reduce_sum(a.nll_b[tid] + a.nll_b[tid + 256], smem);
  float ce = 0.f;
  #pragma unroll
  for (int i = 0; i < 32; ++i) ce += a.ce_part[i * 256 + tid];
  const float sce = block_reduce_sum(ce, smem);
  const float sl2 = block_reduce_sum((tid < 64) ? a.l2_part[tid] : 0.f, smem);
  if (tid == 0) {
    const float nll = snll / (float)Bsz;
    const float marg = -sce / (float)Bsz;
    const float l2v = WDf * sl2;
    a.out4[0] = nll;
    a.out4[1] = marg;
    a.out4[2] = l2v;
    a.out4[3] = l2v + nll;
  }
}

// ---------------- phase-0 unit dispatch ----------------
__device__ __forceinline__ void dev_phase0(int u, int tid, const MegaArgs& a, float* smem) {
  if (u < 64) {
    dev_gemm32(a.X, a.W1, a.b1, a.h1, 512, 128, 512, u & 3, u >> 2, smem, true);
  } else if (u < 128) {
    dev_l2(u - 64, tid, a, smem);
  } else if (u < 136) {
    dev_rprep(u - 128, tid, a.rss, a.Rb, a.sqrtcov);
  } else {
    dev_nprep(u - 136, tid, a.noise, a.nfB);
  }
}

// ================= cooperative mega-kernel =================
__global__ __launch_bounds__(256) void mega(MegaArgs a) {
  cg::grid_group g = cg::this_grid();
  __shared__ float smem[4608];
  const int nb = (int)gridDim.x;
  const int bid = (int)blockIdx.x;
  const int tid = (int)threadIdx.x;

  // phase 0: gemm1 | l2 | rprep | nprep
  for (int u = bid; u < 936; u += nb) dev_phase0(u, tid, a, smem);
  g.sync();
  // phase 1: gemm2
  for (int u = bid; u < 128; u += nb)
    dev_gemm32(a.h1, a.W2, a.b2, a.h2, 512, 256, 128, u & 7, u >> 3, smem, true);
  g.sync();
  // phase 2: gemm3
  for (int u = bid; u < 128; u += nb)
    dev_gemm32(a.h2, a.W3, a.b3, a.feat, 512, 256, 256, u & 7, u >> 3, smem, true);
  g.sync();
  // phase 3: mu GEMM + epilogue
  for (int u = bid; u < 256; u += nb)
    dev_gemm32_mu(a, u & 15, u >> 4, smem);
  g.sync();
  // phase 4: logprob (nb is a multiple of 256; nsg = nb/256)
  {
    const int nsg = nb >> 8;
    const int bt = bid & 31, ctg = (bid >> 5) & 7, sg = bid >> 8;
    const int lo = (Ssz * sg) / nsg, hi = (Ssz * (sg + 1)) / nsg;
    dev_logprob(bt, ctg, lo, hi, tid, a.nfB, a.Rb, a.rmuB, a.yB, a.lp_part);
  }
  g.sync();
  // phase 5: nll per b
  for (int b = bid; b < Bsz; b += nb) dev_nll(b, tid, a.lp_part, a.nll_b, smem);
  g.sync();
  // phase 6: finals
  if (bid == 0) dev_finals(tid, a, smem);
}

// ================= fallback standalone kernels =================
__global__ __launch_bounds__(256) void k_prep(MegaArgs a) {
  __shared__ float smem[4608];
  dev_phase0((int)blockIdx.x, (int)threadIdx.x, a, smem);
}
__global__ __launch_bounds__(256) void k_gemm2(MegaArgs a) {
  __shared__ float smem[4608];
  dev_gemm32(a.h1, a.W2, a.b2, a.h2, 512, 256, 128, blockIdx.x & 7, blockIdx.x >> 3, smem, true);
}
__global__ __launch_bounds__(256) void k_gemm3(MegaArgs a) {
  __shared__ float smem[4608];
  dev_gemm32(a.h2, a.W3, a.b3, a.feat, 512, 256, 256, blockIdx.x & 7, blockIdx.x >> 3, smem, true);
}
__global__ __launch_bounds__(256) void k_gemmmu(MegaArgs a) {
  __shared__ float smem[4608];
  dev_gemm32_mu(a, blockIdx.x & 15, blockIdx.x >> 4, smem);
}
__global__ __launch_bounds__(256, 8) void k_logprob(MegaArgs a) {   // grid 2560
  const int bid = (int)blockIdx.x;
  const int nsg = (int)gridDim.x >> 8;
  const int bt = bid & 31, ctg = (bid >> 5) & 7, sg = bid >> 8;
  const int lo = (Ssz * sg) / nsg, hi = (Ssz * (sg + 1)) / nsg;
  dev_logprob(bt, ctg, lo, hi, (int)threadIdx.x, a.nfB, a.Rb, a.rmuB, a.yB, a.lp_part);
}
__global__ __launch_bounds__(256) void k_nll(MegaArgs a) {          // grid 512
  __shared__ float smem[512];
  dev_nll((int)blockIdx.x, (int)threadIdx.x, a.lp_part, a.nll_b, smem);
}
__global__ __launch_bounds__(256) void k_finals(MegaArgs a) {
  __shared__ float smem[8];
  dev_finals((int)threadIdx.x, a, smem);
}

// ---------------- launch ----------------
extern "C" void kernel_launch(void* const* d_in, const int* in_sizes, int n_in,
                              void* d_out, int out_size, void* d_ws, size_t ws_size,
                              hipStream_t stream) {
  float* ws = (float*)d_ws;
  MegaArgs a;
  a.X = (const float*)d_in[0];
  a.Y = (const float*)d_in[1];
  a.noise = (const float*)d_in[2];
  a.W1 = (const float*)d_in[3];
  a.b1 = (const float*)d_in[4];
  a.W2 = (const float*)d_in[5];
  a.b2 = (const float*)d_in[6];
  a.W3 = (const float*)d_in[7];
  a.b3 = (const float*)d_in[8];
  a.Wmu = (const float*)d_in[9];
  a.bmu = (const float*)d_in[10];
  a.rss = (const float*)d_in[11];

  // lp_part aliases trunk temporaries (h*, feat dead before phase-4 writes)
  a.lp_part = ws;                  // 32*100*512 = 1638400
  a.h1 = ws;                       // 512*128
  a.h2 = a.h1 + 65536;             // 512*256
  a.feat = a.h2 + 131072;          // 512*256 (ends 327680 < 1638400)
  float* B0 = ws + 1638400;
  a.sqrtcov = B0;                  // 512
  a.rmuB = a.sqrtcov + 512;        // 512*512
  a.yB = a.rmuB + 262144;          // 512*512
  a.ce_part = a.yB + 262144;       // 16*512
  a.nll_b = a.ce_part + 8192;      // 512
  a.l2_part = a.nll_b + 512;       // 128
  a.Rb = (short*)(a.l2_part + 128);            // 512*64 shorts
  a.nfB = (short*)(a.l2_part + 128 + 16384);   // 100*32*128*8 shorts

  a.out_prob = (float*)d_out;
  a.out4 = a.out_prob + (size_t)Bsz * Csz;

  // cooperative grid sizing (pure host queries; deterministic)
  int dev = 0;
  (void)hipGetDevice(&dev);
  int cus = 0;
  (void)hipDeviceGetAttribute(&cus, hipDeviceAttributeMultiprocessorCount, dev);
  int bpc = 0;
  (void)hipOccupancyMaxActiveBlocksPerMultiprocessor(&bpc, mega, 256, 0);
  long grid = (long)bpc * (long)cus;
  if (grid > 2048) grid = 2048;
  grid &= ~255L;                   // phase 4 requires a multiple of 256

  hipError_t e = hipErrorUnknown;
  if (grid >= 256) {
    void* kp[] = { (void*)&a };
    e = hipLaunchCooperativeKernel(mega, dim3((unsigned)grid), dim3(256), kp, 0, stream);
  }
  if (e != hipSuccess) {
    // fallback: same device code as discrete launches
    k_prep<<<dim3(936), 256, 0, stream>>>(a);
    k_gemm2<<<dim3(128), 256, 0, stream>>>(a);
    k_gemm3<<<dim3(128), 256, 0, stream>>>(a);
    k_gemmmu<<<dim3(256), 256, 0, stream>>>(a);
    k_logprob<<<dim3(2560), 256, 0, stream>>>(a);
    k_nll<<<dim3(512), 256, 0, stream>>>(a);
    k_finals<<<dim3(1), 256, 0, stream>>>(a);
  }
}

// Round 9
// 93.157 us; speedup vs baseline: 4.7045x; 4.7045x over previous
//
#include <hip/hip_runtime.h>
#include <cstddef>

#define EPS1f 1e-6f
#define WDf   1e-5f

constexpr int Bsz = 512, Csz = 500, Zsz = 64, Ssz = 100;

typedef short bf16x8 __attribute__((ext_vector_type(8)));
typedef float f32x4 __attribute__((ext_vector_type(4)));

__device__ inline short f2bf(float f) {
  union { float f; unsigned u; } v; v.f = f;
  unsigned r = (v.u + 0x7fffu + ((v.u >> 16) & 1u)) >> 16;   // RNE
  return (short)r;
}

// log( Phi(t)*(1-eps) + eps/2 )  via A&S 7.1.26 erfc approx (|err|<=1.5e-7)
__device__ inline float log_probit(float t) {
  const float u = t * -0.70710678118654752f;
  const float au = fabsf(u);
  const float s = 1.f / fmaf(0.3275911f, au, 1.f);
  float p = fmaf(1.061405429f, s, -1.453152027f);
  p = fmaf(p, s, 1.421413741f);
  p = fmaf(p, s, -0.284496736f);
  p = fmaf(p, s, 0.254829592f);
  p = p * s;
  const float e = __expf(-au * au);
  const float f = p * e;
  const float erfc_u = (u < 0.f) ? (2.f - f) : f;
  const float E = fmaf(0.5f * erfc_u, 1.f - EPS1f, 0.5f * EPS1f);
  return __logf(E);
}

__device__ inline float block_reduce_sum(float v, float* red) {
  #pragma unroll
  for (int off = 32; off > 0; off >>= 1) v += __shfl_down(v, off, 64);
  const int lane = threadIdx.x & 63, wid = threadIdx.x >> 6;
  if (lane == 0) red[wid] = v;
  __syncthreads();
  float r = 0.f;
  if (threadIdx.x == 0) {
    const int nw = blockDim.x >> 6;
    for (int i = 0; i < nw; ++i) r += red[i];
  }
  __syncthreads();
  return r;   // valid in thread 0 only
}

// ---------------- 32x32 double-buffered GEMM body ----------------
__device__ __forceinline__ void gemm32_body(
    const float* __restrict__ A, const float* __restrict__ W,
    const float* __restrict__ bias, float* __restrict__ out,
    int M, int N, int K, int bn0, int bm0, float* As_, float* Ws_, bool relu) {
  const int tid = threadIdx.x;
  const int bn = bn0 * 32, bm = bm0 * 32;
  const int sm = tid >> 3, sk4 = (tid & 7) * 4;
  const int sk = tid >> 3, sn4 = (tid & 7) * 4;
  const int tn = tid & 15, tm = tid >> 4;
  #define AS_(b, k, m) As_[(b) * 1152 + (k) * 36 + (m)]
  #define WS_(b, k, n) Ws_[(b) * 1152 + (k) * 36 + (n)]
  auto loadW = [&](int kt, float4& wv) {
    const float* wrow = W + (size_t)(kt + sk) * N;
    const int nn = bn + sn4;
    if (nn + 3 < N) wv = *reinterpret_cast<const float4*>(wrow + nn);
    else {
      wv.x = (nn + 0 < N) ? wrow[nn + 0] : 0.f;
      wv.y = (nn + 1 < N) ? wrow[nn + 1] : 0.f;
      wv.z = (nn + 2 < N) ? wrow[nn + 2] : 0.f;
      wv.w = (nn + 3 < N) ? wrow[nn + 3] : 0.f;
    }
  };
  {
    float4 av = *reinterpret_cast<const float4*>(A + (size_t)(bm + sm) * K + sk4);
    float4 wv; loadW(0, wv);
    AS_(0, sk4 + 0, sm) = av.x; AS_(0, sk4 + 1, sm) = av.y;
    AS_(0, sk4 + 2, sm) = av.z; AS_(0, sk4 + 3, sm) = av.w;
    *reinterpret_cast<float4*>(&WS_(0, sk, sn4)) = wv;
  }
  __syncthreads();
  float acc[2][2] = {};
  int pb = 0;
  for (int kt = 0; kt < K; kt += 32) {
    const bool more = (kt + 32) < K;
    float4 av2, wv2;
    if (more) {
      av2 = *reinterpret_cast<const float4*>(A + (size_t)(bm + sm) * K + kt + 32 + sk4);
      loadW(kt + 32, wv2);
    }
    #pragma unroll
    for (int k = 0; k < 32; ++k) {
      const float2 a = *reinterpret_cast<const float2*>(&AS_(pb, k, tm * 2));
      const float2 w = *reinterpret_cast<const float2*>(&WS_(pb, k, tn * 2));
      acc[0][0] = fmaf(a.x, w.x, acc[0][0]);
      acc[0][1] = fmaf(a.x, w.y, acc[0][1]);
      acc[1][0] = fmaf(a.y, w.x, acc[1][0]);
      acc[1][1] = fmaf(a.y, w.y, acc[1][1]);
    }
    if (more) {
      const int nb = pb ^ 1;
      AS_(nb, sk4 + 0, sm) = av2.x; AS_(nb, sk4 + 1, sm) = av2.y;
      AS_(nb, sk4 + 2, sm) = av2.z; AS_(nb, sk4 + 3, sm) = av2.w;
      *reinterpret_cast<float4*>(&WS_(nb, sk, sn4)) = wv2;
      __syncthreads();
      pb = nb;
    }
  }
  #pragma unroll
  for (int j = 0; j < 2; ++j) {
    const int n = bn + tn * 2 + j;
    if (n >= N) continue;
    const float bv = bias[n];
    #pragma unroll
    for (int i = 0; i < 2; ++i) {
      const int m = bm + tm * 2 + i;
      float v = acc[i][j] + bv;
      if (relu) v = fmaxf(v, 0.f);
      out[(size_t)m * N + n] = v;
    }
  }
  #undef AS_
  #undef WS_
}

// ---------------- PREP: nprep(0-799) | rprep(800-807) | l2(808-871) | gemm1(872-935) ----------------
__global__ __launch_bounds__(256) void prep_kernel(
    const float* __restrict__ noise, short* __restrict__ nfB,
    const float* __restrict__ R, short* __restrict__ Rb, float* __restrict__ sqrtcov,
    const float* __restrict__ X, const float* __restrict__ W1,
    const float* __restrict__ b1, float* __restrict__ h1,
    const float* __restrict__ W2, const float* __restrict__ W3,
    const float* __restrict__ Wmu, float* __restrict__ l2_part) {
  __shared__ float smem[2304 * 2];
  const int blk = blockIdx.x;
  const int tid = threadIdx.x;
  if (blk < 800) {
    const int g = blk * 256 + tid;       // 204800
    const int s = g >> 11;
    const int r = g & 2047;
    const int bt = r >> 6;
    const int ln = r & 63;
    const int cl = ln & 15, grp = ln >> 4;
    const float* src = noise + ((size_t)(s * 512 + bt * 16 + cl) * 64 + grp * 8);
    const float4 a = *reinterpret_cast<const float4*>(src);
    const float4 b = *reinterpret_cast<const float4*>(src + 4);
    const float4 c = *reinterpret_cast<const float4*>(src + 32);
    const float4 d = *reinterpret_cast<const float4*>(src + 36);
    bf16x8* dst = reinterpret_cast<bf16x8*>(nfB);
    const int u = (s * 32 + bt) * 128 + ln;
    dst[u]      = bf16x8{ f2bf(a.x), f2bf(a.y), f2bf(a.z), f2bf(a.w),
                          f2bf(b.x), f2bf(b.y), f2bf(b.z), f2bf(b.w) };
    dst[u + 64] = bf16x8{ f2bf(c.x), f2bf(c.y), f2bf(c.z), f2bf(c.w),
                          f2bf(d.x), f2bf(d.y), f2bf(d.z), f2bf(d.w) };
  } else if (blk < 808) {
    const int idx = (blk - 800) * 256 + tid;   // 0..2047
    const int c = idx >> 2;
    const int zq = (idx & 3) * 16;
    const bool cv = c < Csz;
    const float* src = R + (size_t)c * Zsz + zq;
    float4 r0, r1, r2, r3;
    if (cv) {
      r0 = *reinterpret_cast<const float4*>(src);
      r1 = *reinterpret_cast<const float4*>(src + 4);
      r2 = *reinterpret_cast<const float4*>(src + 8);
      r3 = *reinterpret_cast<const float4*>(src + 12);
    } else {
      r0 = r1 = r2 = r3 = make_float4(0.f, 0.f, 0.f, 0.f);
    }
    float ss = 0.f;
    ss = fmaf(r0.x, r0.x, ss); ss = fmaf(r0.y, r0.y, ss);
    ss = fmaf(r0.z, r0.z, ss); ss = fmaf(r0.w, r0.w, ss);
    ss = fmaf(r1.x, r1.x, ss); ss = fmaf(r1.y, r1.y, ss);
    ss = fmaf(r1.z, r1.z, ss); ss = fmaf(r1.w, r1.w, ss);
    ss = fmaf(r2.x, r2.x, ss); ss = fmaf(r2.y, r2.y, ss);
    ss = fmaf(r2.z, r2.z, ss); ss = fmaf(r2.w, r2.w, ss);
    ss = fmaf(r3.x, r3.x, ss); ss = fmaf(r3.y, r3.y, ss);
    ss = fmaf(r3.z, r3.z, ss); ss = fmaf(r3.w, r3.w, ss);
    short* dst = Rb + (size_t)c * Zsz + zq;
    *reinterpret_cast<bf16x8*>(dst) =
        bf16x8{ f2bf(r0.x), f2bf(r0.y), f2bf(r0.z), f2bf(r0.w),
                f2bf(r1.x), f2bf(r1.y), f2bf(r1.z), f2bf(r1.w) };
    *reinterpret_cast<bf16x8*>(dst + 8) =
        bf16x8{ f2bf(r2.x), f2bf(r2.y), f2bf(r2.z), f2bf(r2.w),
                f2bf(r3.x), f2bf(r3.y), f2bf(r3.z), f2bf(r3.w) };
    ss += __shfl_xor(ss, 1, 64);
    ss += __shfl_xor(ss, 2, 64);
    if ((idx & 3) == 0 && cv) sqrtcov[c] = sqrtf(1.f + ss);
  } else if (blk < 872) {
    const int bid = blk - 808;
    const int gid = bid * 256 + tid;
    const int stride = 64 * 256;
    float s = 0.f;
    for (int i = gid; i < 65536; i += stride) { float v = W1[i]; s = fmaf(v, v, s); }
    for (int i = gid; i < 32768; i += stride) { float v = W2[i]; s = fmaf(v, v, s); }
    for (int i = gid; i < 65536; i += stride) { float v = W3[i]; s = fmaf(v, v, s); }
    for (int i = gid; i < 128000; i += stride) { float v = Wmu[i]; s = fmaf(v, v, s); }
    const float tot = block_reduce_sum(s, smem);
    if (tid == 0) l2_part[bid] = tot;
  } else {
    const int idx = blk - 872;                  // 0..63
    gemm32_body(X, W1, b1, h1, 512, 128, 512, idx & 3, idx >> 2,
                smem, smem + 2304, true);
  }
}

// ---------------- standalone 32x32 GEMM ----------------
template <bool RELU>
__global__ __launch_bounds__(256) void gemm32(
    const float* __restrict__ A, const float* __restrict__ W,
    const float* __restrict__ bias, float* __restrict__ out,
    int M, int N, int K) {
  __shared__ float smem[2304 * 2];
  gemm32_body(A, W, bias, out, M, N, K, blockIdx.x, blockIdx.y,
              smem, smem + 2304, RELU);
}

// ---------------- MU GEMM: -> indiv_prob, CE partials, rmuB/yB [b][c] padded ----------------
__global__ __launch_bounds__(256) void gemm32_mu(
    const float* __restrict__ A, const float* __restrict__ W,
    const float* __restrict__ bias, const float* __restrict__ Y,
    const float* __restrict__ sqrtcov,
    float* __restrict__ out_prob, float* __restrict__ rmuB, float* __restrict__ yB,
    float* __restrict__ ce_part, int M, int N, int K) {
  __shared__ float As[2][32][36];
  __shared__ float Ws[2][32][36];
  const int tid = threadIdx.x;
  const int bn = blockIdx.x * 32, bm = blockIdx.y * 32;
  const int sm = tid >> 3, sk4 = (tid & 7) * 4;
  const int sk = tid >> 3, sn4 = (tid & 7) * 4;
  const int tn = tid & 15, tm = tid >> 4;

  auto loadW = [&](int kt, float4& wv) {
    const float* wrow = W + (size_t)(kt + sk) * N;
    const int nn = bn + sn4;
    if (nn + 3 < N) wv = *reinterpret_cast<const float4*>(wrow + nn);
    else {
      wv.x = (nn + 0 < N) ? wrow[nn + 0] : 0.f;
      wv.y = (nn + 1 < N) ? wrow[nn + 1] : 0.f;
      wv.z = (nn + 2 < N) ? wrow[nn + 2] : 0.f;
      wv.w = (nn + 3 < N) ? wrow[nn + 3] : 0.f;
    }
  };
  {
    float4 av = *reinterpret_cast<const float4*>(A + (size_t)(bm + sm) * K + sk4);
    float4 wv; loadW(0, wv);
    As[0][sk4 + 0][sm] = av.x; As[0][sk4 + 1][sm] = av.y;
    As[0][sk4 + 2][sm] = av.z; As[0][sk4 + 3][sm] = av.w;
    *reinterpret_cast<float4*>(&Ws[0][sk][sn4]) = wv;
  }
  __syncthreads();
  float acc[2][2] = {};
  int pb = 0;
  for (int kt = 0; kt < K; kt += 32) {
    const bool more = (kt + 32) < K;
    float4 av2, wv2;
    if (more) {
      av2 = *reinterpret_cast<const float4*>(A + (size_t)(bm + sm) * K + kt + 32 + sk4);
      loadW(kt + 32, wv2);
    }
    #pragma unroll
    for (int k = 0; k < 32; ++k) {
      const float2 a = *reinterpret_cast<const float2*>(&As[pb][k][tm * 2]);
      const float2 w = *reinterpret_cast<const float2*>(&Ws[pb][k][tn * 2]);
      acc[0][0] = fmaf(a.x, w.x, acc[0][0]);
      acc[0][1] = fmaf(a.x, w.y, acc[0][1]);
      acc[1][0] = fmaf(a.y, w.x, acc[1][0]);
      acc[1][1] = fmaf(a.y, w.y, acc[1][1]);
    }
    if (more) {
      const int nb = pb ^ 1;
      As[nb][sk4 + 0][sm] = av2.x; As[nb][sk4 + 1][sm] = av2.y;
      As[nb][sk4 + 2][sm] = av2.z; As[nb][sk4 + 3][sm] = av2.w;
      *reinterpret_cast<float4*>(&Ws[nb][sk][sn4]) = wv2;
      __syncthreads();
      pb = nb;
    }
  }
  float ce2[2] = {0.f, 0.f};
  #pragma unroll
  for (int i = 0; i < 2; ++i) {
    const int m = bm + tm * 2 + i;
    #pragma unroll
    for (int j = 0; j < 2; ++j) {
      const int n = bn + tn * 2 + j;
      if (n < N) {
        const float v = acc[i][j] + bias[n];
        const float sp = 1.f / (1.f + __expf(-1.70169f * v));
        const float p = fmaf(sp, 1.f - EPS1f, 0.5f * EPS1f);
        const float q = fmaf(1.f - sp, 1.f - EPS1f, 0.5f * EPS1f);
        const float y = Y[(size_t)m * N + n];
        out_prob[(size_t)m * N + n] = p;
        ce2[i] += __logf((y > 0.5f) ? p : q);
        rmuB[(size_t)m * 512 + n] = v * sqrtcov[n];
        yB[(size_t)m * 512 + n] = y;
      }
    }
  }
  #pragma unroll
  for (int off = 1; off < 16; off <<= 1) {
    ce2[0] += __shfl_xor(ce2[0], off, 64);
    ce2[1] += __shfl_xor(ce2[1], off, 64);
  }
  if (tn == 0) {
    const int m0 = bm + tm * 2;
    ce_part[(size_t)blockIdx.x * Bsz + m0] = ce2[0];
    ce_part[(size_t)blockIdx.x * Bsz + m0 + 1] = ce2[1];
  }
}

// ---------------- HOT: s-inner MFMA + probit log-likelihood, 2-way s ILP ----------------
// wave = one (ct, bt) 16c x 16b tile; 10 s per block as 5 pairs. grid = 2560.
__global__ __launch_bounds__(256, 8) void logprob_s(
    const short* __restrict__ nfB, const short* __restrict__ Rb,
    const float* __restrict__ rmuB, const float* __restrict__ yB,
    float* __restrict__ lp_part) {
  const int blk = blockIdx.x;          // sg*256 + ctg*32 + bt
  const int bt = blk & 31;
  const int ctg = (blk >> 5) & 7;
  const int sg = blk >> 8;             // 0..9
  const int wid = threadIdx.x >> 6;
  const int lane = threadIdx.x & 63;
  const int cl = lane & 15, grp = lane >> 4;
  const int ct = ctg * 4 + wid;
  const int c0 = ct * 16, b0 = bt * 16;

  const bf16x8 Rf0 = *reinterpret_cast<const bf16x8*>(Rb + (size_t)(c0 + cl) * 64 + grp * 8);
  const bf16x8 Rf1 = *reinterpret_cast<const bf16x8*>(Rb + (size_t)(c0 + cl) * 64 + 32 + grp * 8);
  const int cb = c0 + grp * 4;
  const float4 rmu4 = *reinterpret_cast<const float4*>(rmuB + (size_t)(b0 + cl) * 512 + cb);
  const float4 y4   = *reinterpret_cast<const float4*>(yB + (size_t)(b0 + cl) * 512 + cb);
  const float sn0 = fmaf(2.f, y4.x, -1.f), sn1 = fmaf(2.f, y4.y, -1.f);
  const float sn2 = fmaf(2.f, y4.z, -1.f), sn3 = fmaf(2.f, y4.w, -1.f);
  const bool v0 = cb + 0 < Csz, v1 = cb + 1 < Csz, v2 = cb + 2 < Csz, v3 = cb + 3 < Csz;

  const bf16x8* nf = reinterpret_cast<const bf16x8*>(nfB);
  const int sbase = sg * 10;
  int base = (sbase * 32 + bt) * 128 + lane;     // stride per s: 4096

  bf16x8 fa0 = nf[base],        fa1 = nf[base + 64];
  bf16x8 fb0 = nf[base + 4096], fb1 = nf[base + 4096 + 64];

  #pragma unroll 1
  for (int i = 0; i < 10; i += 2) {
    bf16x8 na0, na1, nb0, nb1;
    if (i < 8) {
      na0 = nf[base + 8192];  na1 = nf[base + 8192 + 64];
      nb0 = nf[base + 12288]; nb1 = nf[base + 12288 + 64];
    }
    f32x4 accA = {0.f, 0.f, 0.f, 0.f};
    f32x4 accB = {0.f, 0.f, 0.f, 0.f};
    accA = __builtin_amdgcn_mfma_f32_16x16x32_bf16(Rf0, fa0, accA, 0, 0, 0);
    accB = __builtin_amdgcn_mfma_f32_16x16x32_bf16(Rf0, fb0, accB, 0, 0, 0);
    accA = __builtin_amdgcn_mfma_f32_16x16x32_bf16(Rf1, fa1, accA, 0, 0, 0);
    accB = __builtin_amdgcn_mfma_f32_16x16x32_bf16(Rf1, fb1, accB, 0, 0, 0);
    // 8 independent log_probit chains -> compiler interleaves for ILP
    float lpA = 0.f, lpB = 0.f;
    lpA += v0 ? log_probit((accA[0] + rmu4.x) * sn0) : 0.f;
    lpB += v0 ? log_probit((accB[0] + rmu4.x) * sn0) : 0.f;
    lpA += v1 ? log_probit((accA[1] + rmu4.y) * sn1) : 0.f;
    lpB += v1 ? log_probit((accB[1] + rmu4.y) * sn1) : 0.f;
    lpA += v2 ? log_probit((accA[2] + rmu4.z) * sn2) : 0.f;
    lpB += v2 ? log_probit((accB[2] + rmu4.z) * sn2) : 0.f;
    lpA += v3 ? log_probit((accA[3] + rmu4.w) * sn3) : 0.f;
    lpB += v3 ? log_probit((accB[3] + rmu4.w) * sn3) : 0.f;
    lpA += __shfl_xor(lpA, 16, 64);
    lpA += __shfl_xor(lpA, 32, 64);
    lpB += __shfl_xor(lpB, 16, 64);
    lpB += __shfl_xor(lpB, 32, 64);
    if (lane < 16) {
      const int s = sbase + i;
      lp_part[(size_t)(s * 32 + ct) * 512 + b0 + lane] = lpA;
      lp_part[(size_t)((s + 1) * 32 + ct) * 512 + b0 + lane] = lpB;
    }
    base += 8192;
    fa0 = na0; fa1 = na1; fb0 = nb0; fb1 = nb1;
  }
}

// ---------------- fused ct-sum + LSE: one block per b (512 blocks) ----------------
__global__ __launch_bounds__(256) void nll_kernel(const float* __restrict__ lp_part,
                                                  float* __restrict__ nll_b) {
  __shared__ float sm[256], ss[256];
  const int b = blockIdx.x;
  const int tid = threadIdx.x;
  float m = -3.0e38f, se = 0.f;
  if (tid < Ssz) {
    const float* p = lp_part + (size_t)tid * 16384 + b;
    float a0 = 0.f, a1 = 0.f, a2 = 0.f, a3 = 0.f;
    #pragma unroll
    for (int ct = 0; ct < 32; ct += 4) {
      a0 += p[(ct + 0) * 512];
      a1 += p[(ct + 1) * 512];
      a2 += p[(ct + 2) * 512];
      a3 += p[(ct + 3) * 512];
    }
    m = (a0 + a1) + (a2 + a3);
    se = 1.f;
  }
  sm[tid] = m; ss[tid] = se;
  __syncthreads();
  #pragma unroll
  for (int off = 128; off > 0; off >>= 1) {
    if (tid < off) {
      const float m1 = sm[tid], m2 = sm[tid + off];
      const float M = fmaxf(m1, m2);
      ss[tid] = ss[tid] * __expf(m1 - M) + ss[tid + off] * __expf(m2 - M);
      sm[tid] = M;
    }
    __syncthreads();
  }
  if (tid == 0) nll_b[b] = -__logf(ss[0] * (1.f / (float)Ssz)) - sm[0];
}

// ---------------- final scalars ----------------
__global__ __launch_bounds__(256) void finals_kernel(
    const float* __restrict__ nll_b, const float* __restrict__ ce_part,
    const float* __restrict__ l2_part, int nparts, float* __restrict__ out4) {
  __shared__ float red[4];
  const int t = threadIdx.x;
  const float snll = block_reduce_sum(nll_b[t] + nll_b[t + 256], red);
  float ce = 0.f;
  #pragma unroll
  for (int i = 0; i < 32; ++i) ce += ce_part[i * 256 + t];
  const float sce = block_reduce_sum(ce, red);
  const float sl2 = block_reduce_sum((t < nparts) ? l2_part[t] : 0.f, red);
  if (t == 0) {
    const float nll = snll / (float)Bsz;
    const float marg = -sce / (float)Bsz;
    const float l2v = WDf * sl2;
    out4[0] = nll;
    out4[1] = marg;
    out4[2] = l2v;
    out4[3] = l2v + nll;
  }
}

// ---------------- launch ----------------
extern "C" void kernel_launch(void* const* d_in, const int* in_sizes, int n_in,
                              void* d_out, int out_size, void* d_ws, size_t ws_size,
                              hipStream_t stream) {
  const float* X = (const float*)d_in[0];
  const float* Y = (const float*)d_in[1];
  const float* noise = (const float*)d_in[2];
  const float* W1 = (const float*)d_in[3];
  const float* b1 = (const float*)d_in[4];
  const float* W2 = (const float*)d_in[5];
  const float* b2 = (const float*)d_in[6];
  const float* W3 = (const float*)d_in[7];
  const float* b3 = (const float*)d_in[8];
  const float* Wmu = (const float*)d_in[9];
  const float* bmu = (const float*)d_in[10];
  const float* rss = (const float*)d_in[11];

  float* ws = (float*)d_ws;
  // lp_part aliases trunk temporaries (h*, feat dead before logprob writes)
  float* lp_part = ws;                    // 32*100*512 = 1638400
  float* h1 = ws;                         // 512*128
  float* h2 = h1 + 65536;                 // 512*256
  float* feat = h2 + 131072;              // 512*256   (ends 327680 < 1638400)
  float* B0 = ws + 1638400;
  float* sqrtcov = B0;                    // 512
  float* rmuB = sqrtcov + 512;            // 512*512
  float* yB = rmuB + 262144;              // 512*512
  float* ce_part = yB + 262144;           // 16*512
  float* nll_b = ce_part + 8192;          // 512
  float* l2_part = nll_b + 512;           // 128
  short* Rb = (short*)(l2_part + 128);    // 512*64 shorts
  short* nfB = (short*)(l2_part + 128 + 16384);   // 100*32*128*8 shorts

  float* out_prob = (float*)d_out;
  float* out4 = out_prob + (size_t)Bsz * Csz;

  prep_kernel<<<dim3(936), 256, 0, stream>>>(noise, nfB, rss, Rb, sqrtcov,
                                             X, W1, b1, h1, W2, W3, Wmu, l2_part);

  gemm32<true><<<dim3(8, 16), 256, 0, stream>>>(h1, W2, b2, h2, 512, 256, 128);
  gemm32<true><<<dim3(8, 16), 256, 0, stream>>>(h2, W3, b3, feat, 512, 256, 256);
  gemm32_mu<<<dim3(16, 16), 256, 0, stream>>>(feat, Wmu, bmu, Y, sqrtcov,
                                              out_prob, rmuB, yB, ce_part, 512, 500, 256);

  logprob_s<<<dim3(2560), 256, 0, stream>>>(nfB, Rb, rmuB, yB, lp_part);
  nll_kernel<<<dim3(512), 256, 0, stream>>>(lp_part, nll_b);

  finals_kernel<<<dim3(1), 256, 0, stream>>>(nll_b, ce_part, l2_part, 64, out4);
}

// Round 10
// 86.693 us; speedup vs baseline: 5.0552x; 1.0746x over previous
//
#include <hip/hip_runtime.h>
#include <cstddef>

#define EPS1f 1e-6f
#define WDf   1e-5f

constexpr int Bsz = 512, Csz = 500, Zsz = 64, Ssz = 100;

typedef short bf16x8 __attribute__((ext_vector_type(8)));
typedef float f32x4 __attribute__((ext_vector_type(4)));

__device__ inline short f2bf(float f) {
  union { float f; unsigned u; } v; v.f = f;
  unsigned r = (v.u + 0x7fffu + ((v.u >> 16) & 1u)) >> 16;   // RNE
  return (short)r;
}

// log( Phi(t)*(1-eps) + eps/2 )  via A&S 7.1.26 erfc approx (|err|<=1.5e-7)
__device__ inline float log_probit(float t) {
  const float u = t * -0.70710678118654752f;
  const float au = fabsf(u);
  const float s = 1.f / fmaf(0.3275911f, au, 1.f);
  float p = fmaf(1.061405429f, s, -1.453152027f);
  p = fmaf(p, s, 1.421413741f);
  p = fmaf(p, s, -0.284496736f);
  p = fmaf(p, s, 0.254829592f);
  p = p * s;
  const float e = __expf(-au * au);
  const float f = p * e;
  const float erfc_u = (u < 0.f) ? (2.f - f) : f;
  const float E = fmaf(0.5f * erfc_u, 1.f - EPS1f, 0.5f * EPS1f);
  return __logf(E);
}

__device__ inline float block_reduce_sum(float v, float* red) {
  #pragma unroll
  for (int off = 32; off > 0; off >>= 1) v += __shfl_down(v, off, 64);
  const int lane = threadIdx.x & 63, wid = threadIdx.x >> 6;
  if (lane == 0) red[wid] = v;
  __syncthreads();
  float r = 0.f;
  if (threadIdx.x == 0) {
    const int nw = blockDim.x >> 6;
    for (int i = 0; i < nw; ++i) r += red[i];
  }
  __syncthreads();
  return r;   // valid in thread 0 only
}

// ---------------- 32x32 double-buffered GEMM body ----------------
__device__ __forceinline__ void gemm32_body(
    const float* __restrict__ A, const float* __restrict__ W,
    const float* __restrict__ bias, float* __restrict__ out,
    int M, int N, int K, int bn0, int bm0, float* As_, float* Ws_, bool relu) {
  const int tid = threadIdx.x;
  const int bn = bn0 * 32, bm = bm0 * 32;
  const int sm = tid >> 3, sk4 = (tid & 7) * 4;
  const int sk = tid >> 3, sn4 = (tid & 7) * 4;
  const int tn = tid & 15, tm = tid >> 4;
  #define AS_(b, k, m) As_[(b) * 1152 + (k) * 36 + (m)]
  #define WS_(b, k, n) Ws_[(b) * 1152 + (k) * 36 + (n)]
  auto loadW = [&](int kt, float4& wv) {
    const float* wrow = W + (size_t)(kt + sk) * N;
    const int nn = bn + sn4;
    if (nn + 3 < N) wv = *reinterpret_cast<const float4*>(wrow + nn);
    else {
      wv.x = (nn + 0 < N) ? wrow[nn + 0] : 0.f;
      wv.y = (nn + 1 < N) ? wrow[nn + 1] : 0.f;
      wv.z = (nn + 2 < N) ? wrow[nn + 2] : 0.f;
      wv.w = (nn + 3 < N) ? wrow[nn + 3] : 0.f;
    }
  };
  {
    float4 av = *reinterpret_cast<const float4*>(A + (size_t)(bm + sm) * K + sk4);
    float4 wv; loadW(0, wv);
    AS_(0, sk4 + 0, sm) = av.x; AS_(0, sk4 + 1, sm) = av.y;
    AS_(0, sk4 + 2, sm) = av.z; AS_(0, sk4 + 3, sm) = av.w;
    *reinterpret_cast<float4*>(&WS_(0, sk, sn4)) = wv;
  }
  __syncthreads();
  float acc[2][2] = {};
  int pb = 0;
  for (int kt = 0; kt < K; kt += 32) {
    const bool more = (kt + 32) < K;
    float4 av2, wv2;
    if (more) {
      av2 = *reinterpret_cast<const float4*>(A + (size_t)(bm + sm) * K + kt + 32 + sk4);
      loadW(kt + 32, wv2);
    }
    #pragma unroll
    for (int k = 0; k < 32; ++k) {
      const float2 a = *reinterpret_cast<const float2*>(&AS_(pb, k, tm * 2));
      const float2 w = *reinterpret_cast<const float2*>(&WS_(pb, k, tn * 2));
      acc[0][0] = fmaf(a.x, w.x, acc[0][0]);
      acc[0][1] = fmaf(a.x, w.y, acc[0][1]);
      acc[1][0] = fmaf(a.y, w.x, acc[1][0]);
      acc[1][1] = fmaf(a.y, w.y, acc[1][1]);
    }
    if (more) {
      const int nb = pb ^ 1;
      AS_(nb, sk4 + 0, sm) = av2.x; AS_(nb, sk4 + 1, sm) = av2.y;
      AS_(nb, sk4 + 2, sm) = av2.z; AS_(nb, sk4 + 3, sm) = av2.w;
      *reinterpret_cast<float4*>(&WS_(nb, sk, sn4)) = wv2;
      __syncthreads();
      pb = nb;
    }
  }
  #pragma unroll
  for (int j = 0; j < 2; ++j) {
    const int n = bn + tn * 2 + j;
    if (n >= N) continue;
    const float bv = bias[n];
    #pragma unroll
    for (int i = 0; i < 2; ++i) {
      const int m = bm + tm * 2 + i;
      float v = acc[i][j] + bv;
      if (relu) v = fmaxf(v, 0.f);
      out[(size_t)m * N + n] = v;
    }
  }
  #undef AS_
  #undef WS_
}

// ---------------- PREP: nprep(0-799) | rprep(800-807) | l2(808-871) | gemm1(872-935) ----------------
__global__ __launch_bounds__(256) void prep_kernel(
    const float* __restrict__ noise, short* __restrict__ nfB,
    const float* __restrict__ R, short* __restrict__ Rb, float* __restrict__ sqrtcov,
    const float* __restrict__ X, const float* __restrict__ W1,
    const float* __restrict__ b1, float* __restrict__ h1,
    const float* __restrict__ W2, const float* __restrict__ W3,
    const float* __restrict__ Wmu, float* __restrict__ l2_part) {
  __shared__ float smem[2304 * 2];
  const int blk = blockIdx.x;
  const int tid = threadIdx.x;
  if (blk < 800) {
    const int g = blk * 256 + tid;       // 204800
    const int s = g >> 11;
    const int r = g & 2047;
    const int bt = r >> 6;
    const int ln = r & 63;
    const int cl = ln & 15, grp = ln >> 4;
    const float* src = noise + ((size_t)(s * 512 + bt * 16 + cl) * 64 + grp * 8);
    const float4 a = *reinterpret_cast<const float4*>(src);
    const float4 b = *reinterpret_cast<const float4*>(src + 4);
    const float4 c = *reinterpret_cast<const float4*>(src + 32);
    const float4 d = *reinterpret_cast<const float4*>(src + 36);
    bf16x8* dst = reinterpret_cast<bf16x8*>(nfB);
    const int u = (s * 32 + bt) * 128 + ln;
    dst[u]      = bf16x8{ f2bf(a.x), f2bf(a.y), f2bf(a.z), f2bf(a.w),
                          f2bf(b.x), f2bf(b.y), f2bf(b.z), f2bf(b.w) };
    dst[u + 64] = bf16x8{ f2bf(c.x), f2bf(c.y), f2bf(c.z), f2bf(c.w),
                          f2bf(d.x), f2bf(d.y), f2bf(d.z), f2bf(d.w) };
  } else if (blk < 808) {
    const int idx = (blk - 800) * 256 + tid;   // 0..2047
    const int c = idx >> 2;
    const int zq = (idx & 3) * 16;
    const bool cv = c < Csz;
    const float* src = R + (size_t)c * Zsz + zq;
    float4 r0, r1, r2, r3;
    if (cv) {
      r0 = *reinterpret_cast<const float4*>(src);
      r1 = *reinterpret_cast<const float4*>(src + 4);
      r2 = *reinterpret_cast<const float4*>(src + 8);
      r3 = *reinterpret_cast<const float4*>(src + 12);
    } else {
      r0 = r1 = r2 = r3 = make_float4(0.f, 0.f, 0.f, 0.f);
    }
    float ss = 0.f;
    ss = fmaf(r0.x, r0.x, ss); ss = fmaf(r0.y, r0.y, ss);
    ss = fmaf(r0.z, r0.z, ss); ss = fmaf(r0.w, r0.w, ss);
    ss = fmaf(r1.x, r1.x, ss); ss = fmaf(r1.y, r1.y, ss);
    ss = fmaf(r1.z, r1.z, ss); ss = fmaf(r1.w, r1.w, ss);
    ss = fmaf(r2.x, r2.x, ss); ss = fmaf(r2.y, r2.y, ss);
    ss = fmaf(r2.z, r2.z, ss); ss = fmaf(r2.w, r2.w, ss);
    ss = fmaf(r3.x, r3.x, ss); ss = fmaf(r3.y, r3.y, ss);
    ss = fmaf(r3.z, r3.z, ss); ss = fmaf(r3.w, r3.w, ss);
    short* dst = Rb + (size_t)c * Zsz + zq;
    *reinterpret_cast<bf16x8*>(dst) =
        bf16x8{ f2bf(r0.x), f2bf(r0.y), f2bf(r0.z), f2bf(r0.w),
                f2bf(r1.x), f2bf(r1.y), f2bf(r1.z), f2bf(r1.w) };
    *reinterpret_cast<bf16x8*>(dst + 8) =
        bf16x8{ f2bf(r2.x), f2bf(r2.y), f2bf(r2.z), f2bf(r2.w),
                f2bf(r3.x), f2bf(r3.y), f2bf(r3.z), f2bf(r3.w) };
    ss += __shfl_xor(ss, 1, 64);
    ss += __shfl_xor(ss, 2, 64);
    if ((idx & 3) == 0 && cv) sqrtcov[c] = sqrtf(1.f + ss);
  } else if (blk < 872) {
    const int bid = blk - 808;
    const int gid = bid * 256 + tid;
    const int stride = 64 * 256;
    float s = 0.f;
    for (int i = gid; i < 65536; i += stride) { float v = W1[i]; s = fmaf(v, v, s); }
    for (int i = gid; i < 32768; i += stride) { float v = W2[i]; s = fmaf(v, v, s); }
    for (int i = gid; i < 65536; i += stride) { float v = W3[i]; s = fmaf(v, v, s); }
    for (int i = gid; i < 128000; i += stride) { float v = Wmu[i]; s = fmaf(v, v, s); }
    const float tot = block_reduce_sum(s, smem);
    if (tid == 0) l2_part[bid] = tot;
  } else {
    const int idx = blk - 872;                  // 0..63
    gemm32_body(X, W1, b1, h1, 512, 128, 512, idx & 3, idx >> 2,
                smem, smem + 2304, true);
  }
}

// ---------------- standalone 32x32 GEMM ----------------
template <bool RELU>
__global__ __launch_bounds__(256) void gemm32(
    const float* __restrict__ A, const float* __restrict__ W,
    const float* __restrict__ bias, float* __restrict__ out,
    int M, int N, int K) {
  __shared__ float smem[2304 * 2];
  gemm32_body(A, W, bias, out, M, N, K, blockIdx.x, blockIdx.y,
              smem, smem + 2304, RELU);
}

// ---------------- MU GEMM: -> indiv_prob, CE partials, rmuB/yB [b][c] padded ----------------
__global__ __launch_bounds__(256) void gemm32_mu(
    const float* __restrict__ A, const float* __restrict__ W,
    const float* __restrict__ bias, const float* __restrict__ Y,
    const float* __restrict__ sqrtcov,
    float* __restrict__ out_prob, float* __restrict__ rmuB, float* __restrict__ yB,
    float* __restrict__ ce_part, int M, int N, int K) {
  __shared__ float As[2][32][36];
  __shared__ float Ws[2][32][36];
  const int tid = threadIdx.x;
  const int bn = blockIdx.x * 32, bm = blockIdx.y * 32;
  const int sm = tid >> 3, sk4 = (tid & 7) * 4;
  const int sk = tid >> 3, sn4 = (tid & 7) * 4;
  const int tn = tid & 15, tm = tid >> 4;

  auto loadW = [&](int kt, float4& wv) {
    const float* wrow = W + (size_t)(kt + sk) * N;
    const int nn = bn + sn4;
    if (nn + 3 < N) wv = *reinterpret_cast<const float4*>(wrow + nn);
    else {
      wv.x = (nn + 0 < N) ? wrow[nn + 0] : 0.f;
      wv.y = (nn + 1 < N) ? wrow[nn + 1] : 0.f;
      wv.z = (nn + 2 < N) ? wrow[nn + 2] : 0.f;
      wv.w = (nn + 3 < N) ? wrow[nn + 3] : 0.f;
    }
  };
  {
    float4 av = *reinterpret_cast<const float4*>(A + (size_t)(bm + sm) * K + sk4);
    float4 wv; loadW(0, wv);
    As[0][sk4 + 0][sm] = av.x; As[0][sk4 + 1][sm] = av.y;
    As[0][sk4 + 2][sm] = av.z; As[0][sk4 + 3][sm] = av.w;
    *reinterpret_cast<float4*>(&Ws[0][sk][sn4]) = wv;
  }
  __syncthreads();
  float acc[2][2] = {};
  int pb = 0;
  for (int kt = 0; kt < K; kt += 32) {
    const bool more = (kt + 32) < K;
    float4 av2, wv2;
    if (more) {
      av2 = *reinterpret_cast<const float4*>(A + (size_t)(bm + sm) * K + kt + 32 + sk4);
      loadW(kt + 32, wv2);
    }
    #pragma unroll
    for (int k = 0; k < 32; ++k) {
      const float2 a = *reinterpret_cast<const float2*>(&As[pb][k][tm * 2]);
      const float2 w = *reinterpret_cast<const float2*>(&Ws[pb][k][tn * 2]);
      acc[0][0] = fmaf(a.x, w.x, acc[0][0]);
      acc[0][1] = fmaf(a.x, w.y, acc[0][1]);
      acc[1][0] = fmaf(a.y, w.x, acc[1][0]);
      acc[1][1] = fmaf(a.y, w.y, acc[1][1]);
    }
    if (more) {
      const int nb = pb ^ 1;
      As[nb][sk4 + 0][sm] = av2.x; As[nb][sk4 + 1][sm] = av2.y;
      As[nb][sk4 + 2][sm] = av2.z; As[nb][sk4 + 3][sm] = av2.w;
      *reinterpret_cast<float4*>(&Ws[nb][sk][sn4]) = wv2;
      __syncthreads();
      pb = nb;
    }
  }
  float ce2[2] = {0.f, 0.f};
  #pragma unroll
  for (int i = 0; i < 2; ++i) {
    const int m = bm + tm * 2 + i;
    #pragma unroll
    for (int j = 0; j < 2; ++j) {
      const int n = bn + tn * 2 + j;
      if (n < N) {
        const float v = acc[i][j] + bias[n];
        const float sp = 1.f / (1.f + __expf(-1.70169f * v));
        const float p = fmaf(sp, 1.f - EPS1f, 0.5f * EPS1f);
        const float q = fmaf(1.f - sp, 1.f - EPS1f, 0.5f * EPS1f);
        const float y = Y[(size_t)m * N + n];
        out_prob[(size_t)m * N + n] = p;
        ce2[i] += __logf((y > 0.5f) ? p : q);
        rmuB[(size_t)m * 512 + n] = v * sqrtcov[n];
        yB[(size_t)m * 512 + n] = y;
      }
    }
  }
  #pragma unroll
  for (int off = 1; off < 16; off <<= 1) {
    ce2[0] += __shfl_xor(ce2[0], off, 64);
    ce2[1] += __shfl_xor(ce2[1], off, 64);
  }
  if (tn == 0) {
    const int m0 = bm + tm * 2;
    ce_part[(size_t)blockIdx.x * Bsz + m0] = ce2[0];
    ce_part[(size_t)blockIdx.x * Bsz + m0 + 1] = ce2[1];
  }
}

// ---------------- HOT: s-inner MFMA + probit log-likelihood, 2-way s ILP ----------------
// wave = one (ct, bt) 16c x 16b tile; 10 s per block as 5 pairs. grid = 2560.
// (256,5): VGPR cap ~102 -- 2-way dataflow (~90 VGPR) fits WITHOUT spill.
__global__ __launch_bounds__(256, 5) void logprob_s(
    const short* __restrict__ nfB, const short* __restrict__ Rb,
    const float* __restrict__ rmuB, const float* __restrict__ yB,
    float* __restrict__ lp_part) {
  const int blk = blockIdx.x;          // sg*256 + ctg*32 + bt
  const int bt = blk & 31;
  const int ctg = (blk >> 5) & 7;
  const int sg = blk >> 8;             // 0..9
  const int wid = threadIdx.x >> 6;
  const int lane = threadIdx.x & 63;
  const int cl = lane & 15, grp = lane >> 4;
  const int ct = ctg * 4 + wid;
  const int c0 = ct * 16, b0 = bt * 16;

  const bf16x8 Rf0 = *reinterpret_cast<const bf16x8*>(Rb + (size_t)(c0 + cl) * 64 + grp * 8);
  const bf16x8 Rf1 = *reinterpret_cast<const bf16x8*>(Rb + (size_t)(c0 + cl) * 64 + 32 + grp * 8);
  const int cb = c0 + grp * 4;
  const float4 rmu4 = *reinterpret_cast<const float4*>(rmuB + (size_t)(b0 + cl) * 512 + cb);
  const float4 y4   = *reinterpret_cast<const float4*>(yB + (size_t)(b0 + cl) * 512 + cb);
  const float sn0 = fmaf(2.f, y4.x, -1.f), sn1 = fmaf(2.f, y4.y, -1.f);
  const float sn2 = fmaf(2.f, y4.z, -1.f), sn3 = fmaf(2.f, y4.w, -1.f);
  const bool v0 = cb + 0 < Csz, v1 = cb + 1 < Csz, v2 = cb + 2 < Csz, v3 = cb + 3 < Csz;

  const bf16x8* nf = reinterpret_cast<const bf16x8*>(nfB);
  const int sbase = sg * 10;
  int base = (sbase * 32 + bt) * 128 + lane;     // stride per s: 4096

  bf16x8 fa0 = nf[base],        fa1 = nf[base + 64];
  bf16x8 fb0 = nf[base + 4096], fb1 = nf[base + 4096 + 64];

  #pragma unroll 1
  for (int i = 0; i < 10; i += 2) {
    bf16x8 na0, na1, nb0, nb1;
    if (i < 8) {
      na0 = nf[base + 8192];  na1 = nf[base + 8192 + 64];
      nb0 = nf[base + 12288]; nb1 = nf[base + 12288 + 64];
    }
    f32x4 accA = {0.f, 0.f, 0.f, 0.f};
    f32x4 accB = {0.f, 0.f, 0.f, 0.f};
    accA = __builtin_amdgcn_mfma_f32_16x16x32_bf16(Rf0, fa0, accA, 0, 0, 0);
    accB = __builtin_amdgcn_mfma_f32_16x16x32_bf16(Rf0, fb0, accB, 0, 0, 0);
    accA = __builtin_amdgcn_mfma_f32_16x16x32_bf16(Rf1, fa1, accA, 0, 0, 0);
    accB = __builtin_amdgcn_mfma_f32_16x16x32_bf16(Rf1, fb1, accB, 0, 0, 0);
    // 8 independent log_probit chains -> compiler interleaves for ILP
    float lpA = 0.f, lpB = 0.f;
    lpA += v0 ? log_probit((accA[0] + rmu4.x) * sn0) : 0.f;
    lpB += v0 ? log_probit((accB[0] + rmu4.x) * sn0) : 0.f;
    lpA += v1 ? log_probit((accA[1] + rmu4.y) * sn1) : 0.f;
    lpB += v1 ? log_probit((accB[1] + rmu4.y) * sn1) : 0.f;
    lpA += v2 ? log_probit((accA[2] + rmu4.z) * sn2) : 0.f;
    lpB += v2 ? log_probit((accB[2] + rmu4.z) * sn2) : 0.f;
    lpA += v3 ? log_probit((accA[3] + rmu4.w) * sn3) : 0.f;
    lpB += v3 ? log_probit((accB[3] + rmu4.w) * sn3) : 0.f;
    lpA += __shfl_xor(lpA, 16, 64);
    lpA += __shfl_xor(lpA, 32, 64);
    lpB += __shfl_xor(lpB, 16, 64);
    lpB += __shfl_xor(lpB, 32, 64);
    if (lane < 16) {
      const int s = sbase + i;
      lp_part[(size_t)(s * 32 + ct) * 512 + b0 + lane] = lpA;
      lp_part[(size_t)((s + 1) * 32 + ct) * 512 + b0 + lane] = lpB;
    }
    base += 8192;
    fa0 = na0; fa1 = na1; fb0 = nb0; fb1 = nb1;
  }
}

// ---------------- ct-sum: lp_sum[s][b] = sum_ct lp_part[s][ct][b] (coalesced) ----------------
__global__ __launch_bounds__(256) void ctsum(const float* __restrict__ lp_part,
                                             float* __restrict__ lp_sum) {
  const int i = blockIdx.x * 256 + threadIdx.x;   // 51200
  const int s = i >> 9, b = i & 511;
  const float* p = lp_part + (size_t)s * 16384 + b;
  float a0 = 0.f, a1 = 0.f, a2 = 0.f, a3 = 0.f;
  #pragma unroll
  for (int ct = 0; ct < 32; ct += 4) {
    a0 += p[(ct + 0) * 512];
    a1 += p[(ct + 1) * 512];
    a2 += p[(ct + 2) * 512];
    a3 += p[(ct + 3) * 512];
  }
  lp_sum[i] = (a0 + a1) + (a2 + a3);
}

// ---------------- per-b log-sum-exp over S (4-way s-parallel) ----------------
__global__ __launch_bounds__(256) void nll_kernel(const float* __restrict__ lp_sum,
                                                  float* __restrict__ nll_b) {
  __shared__ float sm[4][64], sse[4][64];
  const int bl = threadIdx.x & 63;
  const int sc = threadIdx.x >> 6;
  const int b = blockIdx.x * 64 + bl;
  float m = -3.0e38f, se = 0.f;
  for (int s = sc * 25; s < sc * 25 + 25; ++s) {
    const float v = lp_sum[(size_t)s * Bsz + b];
    const float mn = fmaxf(m, v);
    se = se * __expf(m - mn) + __expf(v - mn);
    m = mn;
  }
  sm[sc][bl] = m; sse[sc][bl] = se;
  __syncthreads();
  if (sc == 0) {
    float M = sm[0][bl];
    #pragma unroll
    for (int i = 1; i < 4; ++i) M = fmaxf(M, sm[i][bl]);
    float SE = 0.f;
    #pragma unroll
    for (int i = 0; i < 4; ++i) SE += sse[i][bl] * __expf(sm[i][bl] - M);
    nll_b[b] = -__logf(SE * (1.f / (float)Ssz)) - M;
  }
}

// ---------------- final scalars ----------------
__global__ __launch_bounds__(256) void finals_kernel(
    const float* __restrict__ nll_b, const float* __restrict__ ce_part,
    const float* __restrict__ l2_part, int nparts, float* __restrict__ out4) {
  __shared__ float red[4];
  const int t = threadIdx.x;
  const float snll = block_reduce_sum(nll_b[t] + nll_b[t + 256], red);
  float ce = 0.f;
  #pragma unroll
  for (int i = 0; i < 32; ++i) ce += ce_part[i * 256 + t];
  const float sce = block_reduce_sum(ce, red);
  const float sl2 = block_reduce_sum((t < nparts) ? l2_part[t] : 0.f, red);
  if (t == 0) {
    const float nll = snll / (float)Bsz;
    const float marg = -sce / (float)Bsz;
    const float l2v = WDf * sl2;
    out4[0] = nll;
    out4[1] = marg;
    out4[2] = l2v;
    out4[3] = l2v + nll;
  }
}

// ---------------- launch ----------------
extern "C" void kernel_launch(void* const* d_in, const int* in_sizes, int n_in,
                              void* d_out, int out_size, void* d_ws, size_t ws_size,
                              hipStream_t stream) {
  const float* X = (const float*)d_in[0];
  const float* Y = (const float*)d_in[1];
  const float* noise = (const float*)d_in[2];
  const float* W1 = (const float*)d_in[3];
  const float* b1 = (const float*)d_in[4];
  const float* W2 = (const float*)d_in[5];
  const float* b2 = (const float*)d_in[6];
  const float* W3 = (const float*)d_in[7];
  const float* b3 = (const float*)d_in[8];
  const float* Wmu = (const float*)d_in[9];
  const float* bmu = (const float*)d_in[10];
  const float* rss = (const float*)d_in[11];

  float* ws = (float*)d_ws;
  // lp_part aliases trunk temporaries (h*, feat dead before logprob writes)
  float* lp_part = ws;                    // 32*100*512 = 1638400
  float* h1 = ws;                         // 512*128
  float* h2 = h1 + 65536;                 // 512*256
  float* feat = h2 + 131072;              // 512*256   (ends 327680 < 1638400)
  float* B0 = ws + 1638400;
  float* sqrtcov = B0;                    // 512
  float* rmuB = sqrtcov + 512;            // 512*512
  float* yB = rmuB + 262144;              // 512*512
  float* ce_part = yB + 262144;           // 16*512
  float* nll_b = ce_part + 8192;          // 512
  float* l2_part = nll_b + 512;           // 128
  float* lp_sum = l2_part + 128;          // 100*512 = 51200
  short* Rb = (short*)(lp_sum + 51200);   // 512*64 shorts
  short* nfB = (short*)(lp_sum + 51200 + 16384);   // 100*32*128*8 shorts

  float* out_prob = (float*)d_out;
  float* out4 = out_prob + (size_t)Bsz * Csz;

  prep_kernel<<<dim3(936), 256, 0, stream>>>(noise, nfB, rss, Rb, sqrtcov,
                                             X, W1, b1, h1, W2, W3, Wmu, l2_part);

  gemm32<true><<<dim3(8, 16), 256, 0, stream>>>(h1, W2, b2, h2, 512, 256, 128);
  gemm32<true><<<dim3(8, 16), 256, 0, stream>>>(h2, W3, b3, feat, 512, 256, 256);
  gemm32_mu<<<dim3(16, 16), 256, 0, stream>>>(feat, Wmu, bmu, Y, sqrtcov,
                                              out_prob, rmuB, yB, ce_part, 512, 500, 256);

  logprob_s<<<dim3(2560), 256, 0, stream>>>(nfB, Rb, rmuB, yB, lp_part);
  ctsum<<<dim3(200), 256, 0, stream>>>(lp_part, lp_sum);
  nll_kernel<<<dim3(8), 256, 0, stream>>>(lp_sum, nll_b);

  finals_kernel<<<dim3(1), 256, 0, stream>>>(nll_b, ce_part, l2_part, 64, out4);
}